// Round 9
// baseline (241.312 us; speedup 1.0000x reference)
//
#include <hip/hip_runtime.h>
#include <math.h>

#define NN 12000
#define EE 384000
#define FF 128
#define NOUT 40
#define BJ_MAX 25
#define NWARM 8
#define EXIT_TOL 3e-3f
#define GEMM_BLOCKS ((NN + 63) / 64)
#define SEG1 3
#define SEG2 6
#define SEG3 9

typedef __attribute__((ext_vector_type(8))) short bf16x8;
typedef __attribute__((ext_vector_type(4))) short s16x4;
typedef __attribute__((ext_vector_type(4))) float f32x4;
typedef unsigned short ushort_t;

__device__ __forceinline__ ushort_t f2bf(float x) {
  unsigned u = __float_as_uint(x);
  unsigned r = (u + 0x7FFFu + ((u >> 16) & 1u)) >> 16;
  return (ushort_t)r;
}
__device__ __forceinline__ float bf2f(ushort_t h) {
  return __uint_as_float(((unsigned)h) << 16);
}
// swizzled byte offset of element (r, c) in a row-major [*][128] bf16 plane
__device__ __forceinline__ int swz(int r, int c) {
  return ((r << 8) + (c << 1)) ^ ((r & 7) << 4);
}

// ============ MFMA Bjorck building blocks (8 waves, 32x64 tile/wave) ============
__device__ __forceinline__ void mm_product(const char* Xh, const char* Xl,
    const char* Yh, const char* Yl, int R0, int C0, int lane, f32x4 (&acc)[2][4]) {
  int rl = lane & 15;
  int kq = (lane >> 4) * 8;
  #pragma unroll
  for (int k0 = 0; k0 < 128; k0 += 32) {
    bf16x8 ah[2], al[2];
    #pragma unroll
    for (int i = 0; i < 2; i++) {
      ah[i] = *(const bf16x8*)(Xh + swz(R0 + i * 16 + rl, k0 + kq));
      al[i] = *(const bf16x8*)(Xl + swz(R0 + i * 16 + rl, k0 + kq));
    }
    #pragma unroll
    for (int j = 0; j < 4; j++) {
      bf16x8 bh = *(const bf16x8*)(Yh + swz(C0 + j * 16 + rl, k0 + kq));
      bf16x8 bl = *(const bf16x8*)(Yl + swz(C0 + j * 16 + rl, k0 + kq));
      #pragma unroll
      for (int i = 0; i < 2; i++) {
        acc[i][j] = __builtin_amdgcn_mfma_f32_16x16x32_bf16(ah[i], bh, acc[i][j], 0, 0, 0);
        acc[i][j] = __builtin_amdgcn_mfma_f32_16x16x32_bf16(ah[i], bl, acc[i][j], 0, 0, 0);
        acc[i][j] = __builtin_amdgcn_mfma_f32_16x16x32_bf16(al[i], bh, acc[i][j], 0, 0, 0);
      }
    }
  }
}

__device__ __forceinline__ void store_C(char* Ch, char* Cl, int R0, int C0,
    int lane, f32x4 (&acc)[2][4]) {
  int cl = lane & 15, rq = (lane >> 4) * 4;
  #pragma unroll
  for (int i = 0; i < 2; i++)
  #pragma unroll
  for (int j = 0; j < 4; j++) {
    int col = C0 + j * 16 + cl;
    int row = R0 + i * 16 + rq;
    s16x4 hv, lv;
    #pragma unroll
    for (int t = 0; t < 4; t++) {
      float x = acc[i][j][t];
      ushort_t h = f2bf(x);
      ushort_t lo = f2bf(x - bf2f(h));
      hv[t] = (short)h; lv[t] = (short)lo;
    }
    *(s16x4*)(Ch + swz(col, row)) = hv;
    *(s16x4*)(Cl + swz(col, row)) = lv;
  }
}

__device__ __forceinline__ void store_CR(char* Ch, char* Cl, char* Rh, char* Rl,
    int R0, int C0, int lane, f32x4 (&acc)[2][4]) {
  int cl = lane & 15, rq = (lane >> 4) * 4;
  #pragma unroll
  for (int i = 0; i < 2; i++)
  #pragma unroll
  for (int j = 0; j < 4; j++) {
    int col = C0 + j * 16 + cl;
    int row = R0 + i * 16 + rq;
    s16x4 hv, lv;
    #pragma unroll
    for (int t = 0; t < 4; t++) {
      float x = acc[i][j][t];
      ushort_t h = f2bf(x);
      ushort_t lo = f2bf(x - bf2f(h));
      hv[t] = (short)h; lv[t] = (short)lo;
    }
    *(s16x4*)(Ch + swz(col, row)) = hv;
    *(s16x4*)(Cl + swz(col, row)) = lv;
    #pragma unroll
    for (int t = 0; t < 4; t++) {
      *(ushort_t*)(Rh + swz(row + t, col)) = (ushort_t)(unsigned short)hv[t];
      *(ushort_t*)(Rl + swz(row + t, col)) = (ushort_t)(unsigned short)lv[t];
    }
  }
}

// ---- one segment of the Bjorck iteration; state (raw LDS image) lives in
// global between segments. Exit check only exists at it>NWARM, i.e. entirely
// inside the last segment -> earlier segments need no flags.
__device__ void bjorck_segment(int L, int s_it, int e_it, int is_last,
    const float* __restrict__ W1, const float* __restrict__ W2,
    ushort_t* __restrict__ wfc, char* __restrict__ state) {
  __shared__ char lds[131072];
  __shared__ float wmax[8];
  char* P0h = lds;
  char* P0l = lds + 32768;
  char* P1h = lds + 65536;
  char* P1l = lds + 98304;
  const float* Wsrc = (L == 0) ? W1 : W2;
  int tid = threadIdx.x;
  int lane = tid & 63;
  int wv = tid >> 6;
  int R0 = (wv >> 1) * 32;
  int C0 = (wv & 1) * 64;
  char* st = state + L * 131072;

  if (s_it == 0) {
    // ---- scaling = 1/sqrt(max_row_abs_sum * max_col_abs_sum) ----
    float* f = (float*)lds;
    if (tid < 256) {
      float s = 0.0f;
      if (tid < 128) {
        for (int j = 0; j < FF; j++) s += fabsf(Wsrc[tid * FF + j]);
      } else {
        int c = tid - 128;
        for (int j = 0; j < FF; j++) s += fabsf(Wsrc[j * FF + c]);
      }
      f[tid] = s;
    }
    __syncthreads();
    if (tid == 0) {
      float rm = 0.0f, cm = 0.0f;
      for (int i = 0; i < 128; i++) { rm = fmaxf(rm, f[i]); cm = fmaxf(cm, f[128 + i]); }
      f[256] = 1.0f / sqrtf(rm * cm);
    }
    __syncthreads();
    float inv_s = f[256];
    __syncthreads();
    // ---- init: v0 = W * inv_s. v.R -> P0, v.C -> P1 ----
    int r = tid >> 2, c0 = (tid & 3) * 32;
    #pragma unroll
    for (int mm = 0; mm < 32; mm += 8) {
      bf16x8 hv, lv;
      #pragma unroll
      for (int t = 0; t < 8; t++) {
        float x = Wsrc[r * FF + c0 + mm + t] * inv_s;
        ushort_t h = f2bf(x);
        ushort_t lo = f2bf(x - bf2f(h));
        hv[t] = (short)h; lv[t] = (short)lo;
      }
      *(bf16x8*)(P0h + swz(r, c0 + mm)) = hv;
      *(bf16x8*)(P0l + swz(r, c0 + mm)) = lv;
      #pragma unroll
      for (int t = 0; t < 8; t++) {
        *(ushort_t*)(P1h + swz(c0 + mm + t, r)) = (ushort_t)(unsigned short)hv[t];
        *(ushort_t*)(P1l + swz(c0 + mm + t, r)) = (ushort_t)(unsigned short)lv[t];
      }
    }
    __syncthreads();
  } else {
    // load state image
    int4* dst = (int4*)lds;
    const int4* src = (const int4*)st;
    for (int i = tid; i < 8192; i += 512) dst[i] = src[i];
    __syncthreads();
  }

  int done = 0;
  for (int it = s_it; it < e_it; it++) {
    float ca, cb, cc;
    if (it < NWARM)       { ca = 3.4445f; cb = -4.7750f; cc = 2.0315f; }
    else if (it == NWARM) { ca = 2.1479f; cb = -1.7258f; cc = 0.5645f; }
    else                  { ca = 1.875f;  cb = -1.25f;   cc = 0.375f; }

    // phase 1: M = v * v^T
    f32x4 m_acc[2][4] = {};
    mm_product(P0h, P0l, P0h, P0l, R0, C0, lane, m_acc);

    if (it > NWARM) {
      int cl = lane & 15, rq = (lane >> 4) * 4;
      float lmax = 0.0f;
      #pragma unroll
      for (int i = 0; i < 2; i++)
      #pragma unroll
      for (int j = 0; j < 4; j++)
      #pragma unroll
      for (int t = 0; t < 4; t++) {
        int row = R0 + i * 16 + rq + t;
        int col = C0 + j * 16 + cl;
        float d = m_acc[i][j][t] - ((row == col) ? 1.0f : 0.0f);
        lmax = fmaxf(lmax, fabsf(d));
      }
      #pragma unroll
      for (int off = 32; off; off >>= 1) lmax = fmaxf(lmax, __shfl_xor(lmax, off));
      if (lane == 0) wmax[wv] = lmax;
      __syncthreads();
      float gmax = 0.0f;
      #pragma unroll
      for (int w = 0; w < 8; w++) gmax = fmaxf(gmax, wmax[w]);
      if (gmax < EXIT_TOL) { done = 1; break; }
    } else {
      __syncthreads();
    }
    store_C(P0h, P0l, R0, C0, lane, m_acc);   // M symmetric
    __syncthreads();

    // phase 2: M2 = M*M; P = ca*I + cb*M + cc*M2
    f32x4 p_acc[2][4] = {};
    mm_product(P0h, P0l, P0h, P0l, R0, C0, lane, p_acc);
    {
      int cl = lane & 15, rq = (lane >> 4) * 4;
      #pragma unroll
      for (int i = 0; i < 2; i++)
      #pragma unroll
      for (int j = 0; j < 4; j++)
      #pragma unroll
      for (int t = 0; t < 4; t++) {
        int row = R0 + i * 16 + rq + t;
        int col = C0 + j * 16 + cl;
        float pv = cb * m_acc[i][j][t] + cc * p_acc[i][j][t];
        if (row == col) pv += ca;
        p_acc[i][j][t] = pv;
      }
    }
    __syncthreads();
    store_C(P0h, P0l, R0, C0, lane, p_acc);   // P symmetric
    __syncthreads();

    // phase 3: v' = P * v
    f32x4 v_acc[2][4] = {};
    mm_product(P0h, P0l, P1h, P1l, R0, C0, lane, v_acc);
    __syncthreads();
    store_CR(P1h, P1l, P0h, P0l, R0, C0, lane, v_acc);
    __syncthreads();
  }

  if (done || is_last) {
    // writeout: row-major v bf16 planes from P0 (unswizzle)
    ushort_t* oh = wfc + L * 32768;
    ushort_t* ol = oh + 16384;
    int r = tid >> 2;
    int q = tid & 3;
    #pragma unroll
    for (int b = 0; b < 4; b++) {
      int c0 = q * 32 + b * 8;
      bf16x8 hv = *(const bf16x8*)(P0h + swz(r, c0));
      bf16x8 lv = *(const bf16x8*)(P0l + swz(r, c0));
      *(bf16x8*)(oh + r * FF + c0) = hv;
      *(bf16x8*)(ol + r * FF + c0) = lv;
    }
  } else {
    // dump state image
    const int4* src = (const int4*)lds;
    int4* dst = (int4*)st;
    for (int i = tid; i < 8192; i += 512) dst[i] = src[i];
  }
}

// ---- 512-thread scan + dinv (companion of segment 2) ----
__device__ void scan512(const int* __restrict__ cnt, int* __restrict__ rowstart,
    const float* __restrict__ degf, float* __restrict__ dinv) {
  __shared__ int sums[512];
  int tid = threadIdx.x;
  const int CH = 24;                 // 24*512 = 12288 >= NN
  int base = tid * CH;
  int local[CH];
  int s = 0;
  #pragma unroll
  for (int m = 0; m < CH; m++) {
    int idx = base + m;
    int v = (idx < NN) ? cnt[idx] : 0;
    local[m] = s;
    s += v;
  }
  sums[tid] = s;
  __syncthreads();
  for (int off = 1; off < 512; off <<= 1) {
    int v = (tid >= off) ? sums[tid - off] : 0;
    __syncthreads();
    sums[tid] += v;
    __syncthreads();
  }
  int excl = (tid > 0) ? sums[tid - 1] : 0;
  #pragma unroll
  for (int m = 0; m < CH; m++) {
    int idx = base + m;
    if (idx < NN) rowstart[idx] = excl + local[m];
  }
  if (tid == 511) rowstart[NN] = sums[511];
  for (int i = tid; i < NN; i += 512) {
    float dv = degf[i];
    dinv[i] = (dv > 0.0f) ? (1.0f / sqrtf(dv)) : 0.0f;
  }
}

// ============ segment kernels with companion work ============
__global__ __launch_bounds__(512) void k1_seg_deg(const int* __restrict__ ei,
    float* __restrict__ degf, int* __restrict__ cnt,
    const float* __restrict__ W1, const float* __restrict__ W2,
    ushort_t* __restrict__ wfc, char* __restrict__ state) {
  if (blockIdx.x >= 2) {
    int e = (blockIdx.x - 2) * 512 + threadIdx.x;
    if (e < EE) {
      atomicAdd(&degf[ei[e]], 1.0f);
      atomicAdd(&cnt[ei[EE + e]], 1);
    }
    return;
  }
  bjorck_segment(blockIdx.x, 0, SEG1, 0, W1, W2, wfc, state);
}

__global__ __launch_bounds__(512) void k2_seg_scan(const int* __restrict__ cnt,
    int* __restrict__ rowstart, const float* __restrict__ degf, float* __restrict__ dinv,
    const float* __restrict__ W1, const float* __restrict__ W2,
    ushort_t* __restrict__ wfc, char* __restrict__ state) {
  if (blockIdx.x == 2) { scan512(cnt, rowstart, degf, dinv); return; }
  bjorck_segment(blockIdx.x, SEG1, SEG2, 0, W1, W2, wfc, state);
}

__global__ __launch_bounds__(512) void k3_seg_scatter(const int* __restrict__ ei,
    const int* __restrict__ rowstart, int* __restrict__ fill, int* __restrict__ srcl,
    const float* __restrict__ W1, const float* __restrict__ W2,
    ushort_t* __restrict__ wfc, char* __restrict__ state) {
  if (blockIdx.x >= 2) {
    int e = (blockIdx.x - 2) * 512 + threadIdx.x;
    if (e < EE) {
      int r = ei[e], c = ei[EE + e];
      int pos = rowstart[c] + atomicAdd(&fill[c], 1);
      srcl[pos] = r;
    }
    return;
  }
  bjorck_segment(blockIdx.x, SEG2, SEG3, 0, W1, W2, wfc, state);
}

// companion: S = adj @ x (NO relu — relu moved into gemm1 epilogue via
// (adj@x)@W1^T associativity), 16 rows / 512-thread block
__global__ __launch_bounds__(512) void k4_seg_spmm(const float* __restrict__ X,
    float* __restrict__ Sout, const float* __restrict__ dinv,
    const int* __restrict__ rowstart, const int* __restrict__ srcl,
    const float* __restrict__ W1, const float* __restrict__ W2,
    ushort_t* __restrict__ wfc, char* __restrict__ state) {
  if (blockIdx.x >= 2) {
    int g = threadIdx.x >> 5, lane32 = threadIdx.x & 31;
    int row = (blockIdx.x - 2) * 16 + g;
    int s = rowstart[row], e = rowstart[row + 1];
    const float4* G4 = (const float4*)X;
    float4 a0 = make_float4(0.f, 0.f, 0.f, 0.f);
    float4 a1 = make_float4(0.f, 0.f, 0.f, 0.f);
    int p = s;
    for (; p + 2 <= e; p += 2) {
      int r0 = srcl[p], r1 = srcl[p + 1];
      float d0 = dinv[r0], d1 = dinv[r1];
      float4 g0 = G4[r0 * 32 + lane32];
      float4 g1 = G4[r1 * 32 + lane32];
      a0.x += d0 * g0.x; a0.y += d0 * g0.y; a0.z += d0 * g0.z; a0.w += d0 * g0.w;
      a1.x += d1 * g1.x; a1.y += d1 * g1.y; a1.z += d1 * g1.z; a1.w += d1 * g1.w;
    }
    if (p < e) {
      int r0 = srcl[p];
      float d0 = dinv[r0];
      float4 g0 = G4[r0 * 32 + lane32];
      a0.x += d0 * g0.x; a0.y += d0 * g0.y; a0.z += d0 * g0.z; a0.w += d0 * g0.w;
    }
    float dc = dinv[row];
    float4 o;
    o.x = dc * (a0.x + a1.x); o.y = dc * (a0.y + a1.y);
    o.z = dc * (a0.z + a1.z); o.w = dc * (a0.w + a1.w);
    ((float4*)Sout)[row * 32 + lane32] = o;
    return;
  }
  bjorck_segment(blockIdx.x, SEG3, BJ_MAX, 1, W1, W2, wfc, state);
}

// ---------------- MFMA GEMM: Out[N][128] = X @ v^T (+optional relu) ----------------
__global__ __launch_bounds__(256) void gemm_mfma(const float* __restrict__ X,
    const ushort_t* __restrict__ wc, float* __restrict__ Out, int do_relu) {
  __shared__ char xlds[32768];
  char* Xh = xlds;
  char* Xl = xlds + 16384;
  int tid = threadIdx.x;
  int row0 = blockIdx.x * 64;

  {
    int r = tid >> 2;
    int q = (tid & 3) * 32;
    int gr = row0 + r;
    #pragma unroll
    for (int b = 0; b < 32; b += 8) {
      bf16x8 hv, lv;
      if (gr < NN) {
        const float4* xp4 = (const float4*)(X + gr * FF + q + b);
        float4 v0 = xp4[0];
        float4 v1 = xp4[1];
        float xv[8] = {v0.x, v0.y, v0.z, v0.w, v1.x, v1.y, v1.z, v1.w};
        #pragma unroll
        for (int t = 0; t < 8; t++) {
          ushort_t h = f2bf(xv[t]);
          hv[t] = (short)h;
          lv[t] = (short)f2bf(xv[t] - bf2f(h));
        }
      } else {
        #pragma unroll
        for (int t = 0; t < 8; t++) { hv[t] = 0; lv[t] = 0; }
      }
      *(bf16x8*)(Xh + swz(r, q + b)) = hv;
      *(bf16x8*)(Xl + swz(r, q + b)) = lv;
    }
  }
  __syncthreads();

  int lane = tid & 63, wv = tid >> 6;
  int R0 = (wv & 1) * 32;
  int C0 = (wv >> 1) * 64;
  int rl = lane & 15, kq = (lane >> 4) * 8;
  f32x4 acc[2][4] = {};
  #pragma unroll
  for (int k0 = 0; k0 < 128; k0 += 32) {
    bf16x8 ah[2], al[2];
    #pragma unroll
    for (int i = 0; i < 2; i++) {
      ah[i] = *(const bf16x8*)(Xh + swz(R0 + i * 16 + rl, k0 + kq));
      al[i] = *(const bf16x8*)(Xl + swz(R0 + i * 16 + rl, k0 + kq));
    }
    #pragma unroll
    for (int j = 0; j < 4; j++) {
      const ushort_t* bp = wc + (C0 + j * 16 + rl) * FF + k0 + kq;
      bf16x8 bh = *(const bf16x8*)bp;
      bf16x8 bl = *(const bf16x8*)(bp + 16384);
      #pragma unroll
      for (int i = 0; i < 2; i++) {
        acc[i][j] = __builtin_amdgcn_mfma_f32_16x16x32_bf16(ah[i], bh, acc[i][j], 0, 0, 0);
        acc[i][j] = __builtin_amdgcn_mfma_f32_16x16x32_bf16(ah[i], bl, acc[i][j], 0, 0, 0);
        acc[i][j] = __builtin_amdgcn_mfma_f32_16x16x32_bf16(al[i], bh, acc[i][j], 0, 0, 0);
      }
    }
  }
  int rq = (lane >> 4) * 4;
  #pragma unroll
  for (int i = 0; i < 2; i++)
  #pragma unroll
  for (int j = 0; j < 4; j++) {
    int col = C0 + j * 16 + rl;
    #pragma unroll
    for (int t = 0; t < 4; t++) {
      int node = row0 + R0 + i * 16 + rq + t;
      float v = acc[i][j][t];
      if (do_relu) v = fmaxf(v, 0.0f);
      if (node < NN) Out[node * FF + col] = v;
    }
  }
}

// ---------------- fused SpMM2 + relu + head (+log_softmax): 8 rows/block ----------------
__global__ __launch_bounds__(256) void spmm_head(const float* __restrict__ G,
    const float* __restrict__ dinv, const int* __restrict__ rowstart,
    const int* __restrict__ srcl, const float* __restrict__ lw,
    const float* __restrict__ lb, float* __restrict__ out) {
  __shared__ float slw[NOUT * 130];
  __shared__ float slb[64];
  __shared__ float sh[8][128];
  int tid = threadIdx.x;
  for (int i = tid; i < NOUT * 32; i += 256) {
    int r = i >> 5, c4 = i & 31;
    float4 v = ((const float4*)lw)[r * 32 + c4];
    float* dst = slw + r * 130 + c4 * 4;
    dst[0] = v.x; dst[1] = v.y; dst[2] = v.z; dst[3] = v.w;
  }
  if (tid < 64) slb[tid] = (tid < NOUT) ? lb[tid] : 0.0f;

  {
    int g = tid >> 5, lane32 = tid & 31;
    int row = blockIdx.x * 8 + g;
    int s = rowstart[row], e = rowstart[row + 1];
    const float4* G4 = (const float4*)G;
    float4 a0 = make_float4(0.f, 0.f, 0.f, 0.f);
    float4 a1 = make_float4(0.f, 0.f, 0.f, 0.f);
    int p = s;
    for (; p + 2 <= e; p += 2) {
      int r0 = srcl[p], r1 = srcl[p + 1];
      float d0 = dinv[r0], d1 = dinv[r1];
      float4 g0 = G4[r0 * 32 + lane32];
      float4 g1 = G4[r1 * 32 + lane32];
      a0.x += d0 * g0.x; a0.y += d0 * g0.y; a0.z += d0 * g0.z; a0.w += d0 * g0.w;
      a1.x += d1 * g1.x; a1.y += d1 * g1.y; a1.z += d1 * g1.z; a1.w += d1 * g1.w;
    }
    if (p < e) {
      int r0 = srcl[p];
      float d0 = dinv[r0];
      float4 g0 = G4[r0 * 32 + lane32];
      a0.x += d0 * g0.x; a0.y += d0 * g0.y; a0.z += d0 * g0.z; a0.w += d0 * g0.w;
    }
    float dc = dinv[row];
    float4 o;
    o.x = fmaxf(dc * (a0.x + a1.x), 0.f); o.y = fmaxf(dc * (a0.y + a1.y), 0.f);
    o.z = fmaxf(dc * (a0.z + a1.z), 0.f); o.w = fmaxf(dc * (a0.w + a1.w), 0.f);
    ((float4*)&sh[g][0])[lane32] = o;
  }
  __syncthreads();

  int lane = tid & 63, w = tid >> 6;
  int ll = (lane < NOUT) ? lane : 0;
  const float2* wrow = (const float2*)(slw + ll * 130);
  #pragma unroll
  for (int rr = 0; rr < 2; rr++) {
    int lrow = w * 2 + rr;
    int node = blockIdx.x * 8 + lrow;
    const float2* hrow = (const float2*)&sh[lrow][0];
    float val = slb[lane];
    #pragma unroll 4
    for (int k = 0; k < 64; k++) {
      float2 w2 = wrow[k];
      float2 h2 = hrow[k];
      val += w2.x * h2.x + w2.y * h2.y;
    }
    float m = (lane < NOUT) ? val : -INFINITY;
    for (int off = 32; off; off >>= 1) m = fmaxf(m, __shfl_down(m, off));
    m = __shfl(m, 0);
    float ex = (lane < NOUT) ? expf(val - m) : 0.0f;
    float ssum = ex;
    for (int off = 32; off; off >>= 1) ssum += __shfl_down(ssum, off);
    ssum = __shfl(ssum, 0);
    if (lane < NOUT) out[node * NOUT + lane] = val - m - logf(ssum);
  }
}

extern "C" void kernel_launch(void* const* d_in, const int* in_sizes, int n_in,
                              void* d_out, int out_size, void* d_ws, size_t ws_size,
                              hipStream_t stream) {
  const float* x  = (const float*)d_in[0];
  const float* W1 = (const float*)d_in[1];
  const float* W2 = (const float*)d_in[2];
  const float* lw = (const float*)d_in[3];
  const float* lb = (const float*)d_in[4];
  const int*   ei = (const int*)d_in[5];
  float* out = (float*)d_out;

  float* base = (float*)d_ws;
  float* wf   = base;                  // 32768 floats = bf16 h/l planes, 2 weights
  float* degf = wf + 32768;            // NN (memset region start)
  int* cnt      = (int*)(degf + NN);   // NN (memset)
  int* fill     = cnt + NN;            // NN (memset)
  float* dinv = (float*)(fill + NN);   // NN
  int* rowstart = (int*)(dinv + NN);   // NN+1 (pad to 12004)
  int* srcl     = rowstart + 12004;    // EE
  float* bufA = (float*)(srcl + EE);   // NN*FF
  float* bufB = bufA + NN * FF;        // NN*FF
  char* state = (char*)(bufB + NN * FF); // 2 * 131072 bytes bjorck LDS images
  ushort_t* wfc = (ushort_t*)wf;

  (void)hipMemsetAsync(degf, 0, 3 * NN * sizeof(float), stream);

  // 4 bjorck segments (blocks 0,1), each carrying one stage of the
  // bjorck-independent chain as companion blocks:
  k1_seg_deg<<<2 + (EE + 511) / 512, 512, 0, stream>>>(ei, degf, cnt, W1, W2, wfc, state);
  k2_seg_scan<<<3, 512, 0, stream>>>(cnt, rowstart, degf, dinv, W1, W2, wfc, state);
  k3_seg_scatter<<<2 + (EE + 511) / 512, 512, 0, stream>>>(ei, rowstart, fill, srcl, W1, W2, wfc, state);
  k4_seg_spmm<<<2 + NN / 16, 512, 0, stream>>>(x, bufA, dinv, rowstart, srcl, W1, W2, wfc, state);

  // post-bjorck chain: h1 = relu(S @ W1^T); G2 = h1 @ W2^T; out = head(adj-gather(G2))
  gemm_mfma<<<GEMM_BLOCKS, 256, 0, stream>>>(bufA, wfc, bufB, 1);
  gemm_mfma<<<GEMM_BLOCKS, 256, 0, stream>>>(bufB, wfc + 32768, bufA, 0);
  spmm_head<<<NN / 8, 256, 0, stream>>>(bufA, dinv, rowstart, srcl, lw, lb, out);
}